// Round 23
// baseline (3295.649 us; speedup 1.0000x reference)
//
#include <hip/hip_runtime.h>
#include <cstdint>
#include <cstddef>

// Problem constants (from reference: B=16, N=16384, G=512, K=32)
#define NPTS 16384
#define NB   16
#define NG   512
#define NK   32

// Output layout (flat float32, concatenated in return order):
//   neighborhood (16,512,32,3) -> offset 0,       786432 elems
//   center       (16,512,3)    -> offset 786432,  24576  elems
//   idx          (16,512,32)   -> offset 811008,  262144 elems (written as float)
#define NBR_OFF 0
#define CTR_OFF 786432
#define IDX_OFF 811008

// ---------------------------------------------------------------------------
// FPS: one block per batch, 1024 threads, 16 points per thread (registers).
// Plain f32 distance. FPS is INERT: forms {P,A,T,D} bitwise-identical at
// every argmax selection (r12/r13/r18/r21). Kept plain.
// ---------------------------------------------------------------------------
__global__ __launch_bounds__(1024)
void fps_kernel(const float* __restrict__ xyz, float* __restrict__ center_out)
{
#pragma clang fp contract(off)
    const int b = blockIdx.x;
    const int t = threadIdx.x;
    const float* xb = xyz + (size_t)b * NPTS * 3;

    float px[16], py[16], pz[16], dst[16];
#pragma unroll
    for (int k = 0; k < 16; ++k) {
        const int i = t + 1024 * k;
        px[k] = xb[3 * i + 0];
        py[k] = xb[3 * i + 1];
        pz[k] = xb[3 * i + 2];
        dst[k] = 1e10f;
    }

    __shared__ float s_val[16];
    __shared__ int   s_idx[16];
    __shared__ float s_cx, s_cy, s_cz;

    // Step 0: farthest = 0 (owned by thread 0, slot 0)
    if (t == 0) {
        float* co = center_out + (size_t)b * NG * 3;
        co[0] = px[0]; co[1] = py[0]; co[2] = pz[0];
        s_cx = px[0]; s_cy = py[0]; s_cz = pz[0];
    }
    __syncthreads();

    for (int s = 1; s < NG; ++s) {
        const float cx = s_cx, cy = s_cy, cz = s_cz;

        // k descending + ">=" -> ties resolve to lowest global index in-thread
        float m = -1.0f; int mi = 0;
#pragma unroll
        for (int k = 15; k >= 0; --k) {
            const float dx = px[k] - cx;
            const float dy = py[k] - cy;
            const float dz = pz[k] - cz;
            const float d  = dx * dx + dy * dy + dz * dz; // plain
            const float nd = fminf(dst[k], d);
            dst[k] = nd;
            if (nd >= m) { m = nd; mi = t + 1024 * k; }
        }

        // Wave (64-lane) argmax reduction, ties -> lower index
#pragma unroll
        for (int off = 32; off >= 1; off >>= 1) {
            const float ov = __shfl_down(m, off, 64);
            const int   oi = __shfl_down(mi, off, 64);
            if (ov > m || (ov == m && oi < mi)) { m = ov; mi = oi; }
        }
        const int wid = t >> 6;
        if ((t & 63) == 0) { s_val[wid] = m; s_idx[wid] = mi; }
        __syncthreads();

        // Block argmax in wave 0 (lanes 0..15), shfl tree (semilattice)
        if (t < 64) {
            float bv = (t < 16) ? s_val[t] : -1.0f;
            int   bi = (t < 16) ? s_idx[t] : 0x7FFFFFFF;
#pragma unroll
            for (int off = 8; off >= 1; off >>= 1) {
                const float ov = __shfl_down(bv, off, 64);
                const int   oi = __shfl_down(bi, off, 64);
                if (ov > bv || (ov == bv && oi < bi)) { bv = ov; bi = oi; }
            }
            if (t == 0) {
                const float* cp = xb + 3 * (size_t)bi;
                const float gx = cp[0], gy = cp[1], gz = cp[2];
                s_cx = gx; s_cy = gy; s_cz = gz;
                float* co = center_out + ((size_t)b * NG + s) * 3;
                co[0] = gx; co[1] = gy; co[2] = gz;
            }
        }
        __syncthreads();
    }
}

// ---------------------------------------------------------------------------
// kNN: one block per (batch, group) query, 256 threads, 64 points per thread.
// d2 model r23 = (dot=A, sqc=V, sqx=V, S2):
//   sqc = (cx*cx + cz*cz) + cy*cy   [V - CONFIRMED r22: cleared alpha(3136);
//          SLP padded shuffle-tree reduce [m0,m1,m2,0]->[m0+m2,m1]->sum,
//          plain vector fadds, reassociated]
//   sqx = (x*x + z*z) + y*y         [V - same codegen path as sqc (elementwise
//          square + minor-axis reduce). sqx "inertness" among {A,T,D,P} was
//          masking: those flips' |dIdx| < 3136 hid under alpha; with sqc
//          fixed, the surfaced 1152 = sqx A-vs-V flip.]
//   dot = fma(cz,z, fma(cy,y, cx*x)) [A pinned - matmul path (Eigen/BLAS
//          fma ascending); only form clearing delta=11844]
//   d2  = (sqc + sqx) - 2*dot        [S2 pinned]
// Ties: stable lower-first (pinned r19/r20).
// Keys in registers; 32 extraction rounds with cached per-thread local min;
// owner-of-extracted rescans via lexicographic (key, idx) threshold.
// ---------------------------------------------------------------------------
__global__ __launch_bounds__(256)
void knn_kernel(const float* __restrict__ xyz, const float* __restrict__ center,
                float* __restrict__ nbr, float* __restrict__ idxo)
{
#pragma clang fp contract(off)
    const int blk = blockIdx.x;
    const int b = blk >> 9;      // / NG
    const int g = blk & (NG - 1);
    const int t = threadIdx.x;

    const float* xb = xyz + (size_t)b * NPTS * 3;
    const float* cp = center + ((size_t)b * NG + g) * 3;
    const float cx = cp[0], cy = cp[1], cz = cp[2];
    const float sqc = (cx * cx + cz * cz) + cy * cy;         // V (confirmed)

    uint32_t key[64];
    uint32_t bk = 0xFFFFFFFFu; int bi = NPTS;   // local best (min key, min idx)
#pragma unroll
    for (int j = 0; j < 64; ++j) {
        const int i = t + 256 * j;
        const float x = xb[3 * i + 0];
        const float y = xb[3 * i + 1];
        const float z = xb[3 * i + 2];
        const float sqx = (x * x + z * z) + y * y;           // V (matches sqc)
        const float dot = fmaf(cz, z, fmaf(cy, y, cx * x));  // A (pinned)
        const float d2  = (sqc + sqx) - 2.0f * dot;          // S2 (pinned)
        // monotonic float->uint mapping (handles tiny negative d2)
        const uint32_t u = __float_as_uint(d2);
        const uint32_t kk = u ^ (uint32_t)(((int32_t)u >> 31) | (int32_t)0x80000000);
        key[j] = kk;
        if (kk < bk) { bk = kk; bi = i; }  // ascending i + strict < -> low idx ties
    }

    __shared__ uint32_t s_k[4];
    __shared__ int      s_i[4];
    __shared__ int      s_res[NK];
    __shared__ uint32_t s_gk;
    __shared__ int      s_gi;

    const int wid = t >> 6, lane = t & 63;

    for (int r = 0; r < NK; ++r) {
        uint32_t m = bk; int mi = bi;
#pragma unroll
        for (int off = 32; off >= 1; off >>= 1) {
            const uint32_t ov = __shfl_down(m, off, 64);
            const int      oi = __shfl_down(mi, off, 64);
            if (ov < m || (ov == m && oi < mi)) { m = ov; mi = oi; }
        }
        if (lane == 0) { s_k[wid] = m; s_i[wid] = mi; }
        __syncthreads();

        if (t == 0) {
            uint32_t gk = s_k[0]; int gi = s_i[0];
#pragma unroll
            for (int w = 1; w < 4; ++w) {
                if (s_k[w] < gk || (s_k[w] == gk && s_i[w] < gi)) { gk = s_k[w]; gi = s_i[w]; }
            }
            s_res[r] = gi; s_gk = gk; s_gi = gi;
        }
        __syncthreads();

        if (r < NK - 1) {
            const uint32_t gk = s_gk; const int gi = s_gi;
            if (t == (gi & 255)) {
                // rescan own 64 keys: min over pairs lexicographically > (gk, gi)
                bk = 0xFFFFFFFFu; bi = NPTS;
#pragma unroll
                for (int j = 0; j < 64; ++j) {
                    const int i = t + 256 * j;
                    const uint32_t kk = key[j];
                    const bool elig = (kk > gk) || (kk == gk && i > gi);
                    if (elig && (kk < bk || (kk == bk && i < bi))) { bk = kk; bi = i; }
                }
            }
        }
    }
    __syncthreads();

    // Emit: idx (as float) and neighborhood = xyz[idx] - center (f32)
    if (t < NK) {
        const int i = s_res[t];
        const size_t base = (size_t)b * NG + g;
        idxo[base * NK + t] = (float)i;
        const float x = xb[3 * i + 0];
        const float y = xb[3 * i + 1];
        const float z = xb[3 * i + 2];
        float* nb = nbr + (base * NK + t) * 3;
        nb[0] = x - cx; nb[1] = y - cy; nb[2] = z - cz;
    }
}

extern "C" void kernel_launch(void* const* d_in, const int* in_sizes, int n_in,
                              void* d_out, int out_size, void* d_ws, size_t ws_size,
                              hipStream_t stream)
{
    (void)in_sizes; (void)n_in; (void)out_size; (void)d_ws; (void)ws_size;
    const float* xyz = (const float*)d_in[0];
    float* out    = (float*)d_out;
    float* nbr    = out + NBR_OFF;
    float* center = out + CTR_OFF;
    float* idxo   = out + IDX_OFF;

    fps_kernel<<<NB, 1024, 0, stream>>>(xyz, center);
    knn_kernel<<<NB * NG, 256, 0, stream>>>(xyz, center, nbr, idxo);
}

// Round 24
// 1652.152 us; speedup vs baseline: 1.9948x; 1.9948x over previous
//
#include <hip/hip_runtime.h>
#include <cstdint>
#include <cstddef>

// Problem constants (from reference: B=16, N=16384, G=512, K=32)
#define NPTS 16384
#define NB   16
#define NG   512
#define NK   32

// Output layout (flat float32, concatenated in return order):
//   neighborhood (16,512,32,3) -> offset 0,       786432 elems
//   center       (16,512,3)    -> offset 786432,  24576  elems
//   idx          (16,512,32)   -> offset 811008,  262144 elems (written as float)
#define NBR_OFF 0
#define CTR_OFF 786432
#define IDX_OFF 811008

// ---------------------------------------------------------------------------
// FPS: one block per batch, 1024 threads, 16 points per thread (registers).
// Numerics (verified r23): plain f32 direct distance, no FMA; argmax ties ->
// lowest index. Structure: ONE barrier per step (parity-double-buffered wave
// results); every wave redundantly reduces the 16 wave winners and loads the
// winning centroid from global (broadcast, L1/L2 hit) -- removes the second
// barrier + thread-0 serialization of the r23 version.
// ---------------------------------------------------------------------------
__global__ __launch_bounds__(1024)
void fps_kernel(const float* __restrict__ xyz, float* __restrict__ center_out)
{
#pragma clang fp contract(off)
    const int b = blockIdx.x;
    const int t = threadIdx.x;
    const int lane = t & 63;
    const int wid  = t >> 6;
    const float* xb = xyz + (size_t)b * NPTS * 3;

    float px[16], py[16], pz[16], dst[16];
#pragma unroll
    for (int k = 0; k < 16; ++k) {
        const int i = t + 1024 * k;
        px[k] = xb[3 * i + 0];
        py[k] = xb[3 * i + 1];
        pz[k] = xb[3 * i + 2];
        dst[k] = 1e10f;
    }

    __shared__ float s_val[2][16];
    __shared__ int   s_idx[2][16];

    // Step 0: centroid = point 0 (broadcast from global; same bits as before)
    float cx = xb[0], cy = xb[1], cz = xb[2];
    if (t == 0) {
        float* co = center_out + (size_t)b * NG * 3;
        co[0] = cx; co[1] = cy; co[2] = cz;
    }

    for (int s = 1; s < NG; ++s) {
        const int par = s & 1;

        // k descending + ">=" -> ties resolve to lowest global index in-thread
        float m = -1.0f; int mi = 0;
#pragma unroll
        for (int k = 15; k >= 0; --k) {
            const float dx = px[k] - cx;
            const float dy = py[k] - cy;
            const float dz = pz[k] - cz;
            const float d  = dx * dx + dy * dy + dz * dz; // plain (pinned)
            const float nd = fminf(dst[k], d);
            dst[k] = nd;
            if (nd >= m) { m = nd; mi = t + 1024 * k; }
        }

        // Wave argmax reduce, ties -> lower index
#pragma unroll
        for (int off = 32; off >= 1; off >>= 1) {
            const float ov = __shfl_down(m, off, 64);
            const int   oi = __shfl_down(mi, off, 64);
            if (ov > m || (ov == m && oi < mi)) { m = ov; mi = oi; }
        }
        if (lane == 0) { s_val[par][wid] = m; s_idx[par][wid] = mi; }
        __syncthreads();   // the ONLY barrier per step

        // Every wave redundantly reduces the 16 wave winners (semilattice ->
        // order-independent, identical result in all waves)
        float bv = (lane < 16) ? s_val[par][lane] : -1.0f;
        int   bi = (lane < 16) ? s_idx[par][lane] : 0x7FFFFFFF;
#pragma unroll
        for (int off = 8; off >= 1; off >>= 1) {
            const float ov = __shfl_down(bv, off, 64);
            const int   oi = __shfl_down(bi, off, 64);
            if (ov > bv || (ov == bv && oi < bi)) { bv = ov; bi = oi; }
        }
        bi = __shfl(bi, 0, 64);
        const float* cp = xb + 3 * (size_t)bi;
        cx = cp[0]; cy = cp[1]; cz = cp[2];
        if (t == 0) {
            float* co = center_out + ((size_t)b * NG + s) * 3;
            co[0] = cx; co[1] = cy; co[2] = cz;
        }
        // next step writes s_val[par^1] -> no second barrier needed
    }
}

// ---------------------------------------------------------------------------
// kNN: one block per (batch, group) query, 512 threads, 32 keys per thread
// IN REGISTERS (r23's key[64] at VGPR=72 spilled to scratch -> the 2168us).
// Numerics (verified r23): sqc/sqx = V-form (x*x + z*z) + y*y (plain);
// dot = fma(cz,z, fma(cy,y, cx*x)); d2 = (sqc+sqx) - 2*dot; stable ties.
// Selection: exact 3-pass MSB radix select (12-bit digits, 4096-bin LDS
// histogram, block scan) finds T = exact 32nd-smallest key; collect keys
// < T plus ties == T; rank-sort <=~40 candidates by (key, idx) -> identical
// result to the serial 32-round extraction, ~40x cheaper.
// ---------------------------------------------------------------------------
#define KT  512
#define KPT 32

__global__ __launch_bounds__(512)
void knn_kernel(const float* __restrict__ xyz, const float* __restrict__ center,
                float* __restrict__ nbr, float* __restrict__ idxo)
{
#pragma clang fp contract(off)
    const int blk = blockIdx.x;
    const int b = blk >> 9;      // / NG
    const int g = blk & (NG - 1);
    const int t = threadIdx.x;

    const float* xb = xyz + (size_t)b * NPTS * 3;
    const float* cp = center + ((size_t)b * NG + g) * 3;
    const float cx = cp[0], cy = cp[1], cz = cp[2];
    const float sqc = (cx * cx + cz * cz) + cy * cy;         // V (pinned)

    uint32_t key[KPT];
#pragma unroll
    for (int j = 0; j < KPT; ++j) {
        const int i = t + KT * j;
        const float x = xb[3 * i + 0];
        const float y = xb[3 * i + 1];
        const float z = xb[3 * i + 2];
        const float sqx = (x * x + z * z) + y * y;           // V (pinned)
        const float dot = fmaf(cz, z, fmaf(cy, y, cx * x));  // A (pinned)
        const float d2  = (sqc + sqx) - 2.0f * dot;          // S2 (pinned)
        const uint32_t u = __float_as_uint(d2);
        key[j] = u ^ (uint32_t)(((int32_t)u >> 31) | (int32_t)0x80000000);
    }

    __shared__ uint32_t hist[4096];
    __shared__ uint32_t partial[KT];
    __shared__ uint32_t s_prefix, s_need;
    __shared__ uint32_t nLess, nEq;
    __shared__ uint32_t outK[32];
    __shared__ int      outI[32];
    __shared__ int      eqI[256];
    __shared__ int      s_res[NK];

    if (t == 0) { s_prefix = 0u; s_need = 32u; nLess = 0u; nEq = 0u; }

    // One radix pass: histogram digit (k>>SHIFT)&0xFFF over candidates whose
    // masked bits match the prefix; block-scan to find the bin containing the
    // s_need-th smallest; update prefix/need. Exact, deterministic.
#define RADIX_PASS(SHIFT, PMASK)                                              \
    {                                                                         \
        for (int h = t; h < 4096; h += KT) hist[h] = 0u;                      \
        __syncthreads();                                                      \
        const uint32_t pref_ = s_prefix;                                      \
        _Pragma("unroll")                                                     \
        for (int j = 0; j < KPT; ++j) {                                       \
            const uint32_t k_ = key[j];                                       \
            if ((k_ & (PMASK)) == pref_)                                      \
                atomicAdd(&hist[(k_ >> (SHIFT)) & 0xFFFu], 1u);               \
        }                                                                     \
        __syncthreads();                                                      \
        partial[t] = hist[t*8+0] + hist[t*8+1] + hist[t*8+2] + hist[t*8+3]    \
                   + hist[t*8+4] + hist[t*8+5] + hist[t*8+6] + hist[t*8+7];   \
        __syncthreads();                                                      \
        if (t < 64) {                                                         \
            uint32_t c_ = 0;                                                  \
            _Pragma("unroll")                                                 \
            for (int r = 0; r < 8; ++r) c_ += partial[t*8 + r];               \
            uint32_t inc_ = c_;                                               \
            _Pragma("unroll")                                                 \
            for (int off = 1; off < 64; off <<= 1) {                          \
                const uint32_t v_ = __shfl_up(inc_, off, 64);                 \
                if (t >= off) inc_ += v_;                                     \
            }                                                                 \
            const uint32_t exc_ = inc_ - c_;                                  \
            const uint32_t needv_ = s_need;                                   \
            if (exc_ < needv_ && needv_ <= inc_) {                            \
                uint32_t acc_ = exc_;                                         \
                int p_ = t * 8;                                               \
                while (acc_ + partial[p_] < needv_) { acc_ += partial[p_]; ++p_; } \
                int bin_ = p_ * 8;                                            \
                while (acc_ + hist[bin_] < needv_) { acc_ += hist[bin_]; ++bin_; } \
                s_prefix = pref_ | ((uint32_t)bin_ << (SHIFT));               \
                s_need   = needv_ - acc_;                                     \
            }                                                                 \
        }                                                                     \
        __syncthreads();                                                      \
    }

    RADIX_PASS(20, 0x00000000u)   // bits [31:20]
    RADIX_PASS(8,  0xFFF00000u)   // bits [19:8]
    RADIX_PASS(0,  0xFFFFFF00u)   // bits [11:0] (overlap [11:8] already fixed)
#undef RADIX_PASS

    const uint32_t T = s_prefix;  // exact 32nd-smallest key value

    // Collect: all keys < T (count <= 31) and ties == T (cap 256, arrival order)
#pragma unroll
    for (int j = 0; j < KPT; ++j) {
        const uint32_t k_ = key[j];
        const int i = t + KT * j;
        if (k_ < T) {
            const uint32_t p = atomicAdd(&nLess, 1u);
            outK[p] = k_; outI[p] = i;
        } else if (k_ == T) {
            const uint32_t p = atomicAdd(&nEq, 1u);
            if (p < 256u) eqI[p] = i;
        }
    }
    __syncthreads();

    // Rank-sort candidates by (key, idx); first NK ranks are the answer in
    // exactly the stable (key asc, idx asc) order the reference produces.
    const int nl = (int)nLess;
    const int ne = (int)(nEq > 256u ? 256u : nEq);
    const int n  = nl + ne;
    if (t < n) {
        const uint32_t myK = (t < nl) ? outK[t] : T;
        const int      myI = (t < nl) ? outI[t] : eqI[t - nl];
        int rank = 0;
        for (int s = 0; s < n; ++s) {
            const uint32_t sK = (s < nl) ? outK[s] : T;
            const int      sI = (s < nl) ? outI[s] : eqI[s - nl];
            if (sK < myK || (sK == myK && sI < myI)) ++rank;
        }
        if (rank < NK) s_res[rank] = myI;
    }
    __syncthreads();

    // Emit: idx (as float) and neighborhood = xyz[idx] - center (f32)
    if (t < NK) {
        const int i = s_res[t];
        const size_t base = (size_t)b * NG + g;
        idxo[base * NK + t] = (float)i;
        const float x = xb[3 * i + 0];
        const float y = xb[3 * i + 1];
        const float z = xb[3 * i + 2];
        float* nb = nbr + (base * NK + t) * 3;
        nb[0] = x - cx; nb[1] = y - cy; nb[2] = z - cz;
    }
}

extern "C" void kernel_launch(void* const* d_in, const int* in_sizes, int n_in,
                              void* d_out, int out_size, void* d_ws, size_t ws_size,
                              hipStream_t stream)
{
    (void)in_sizes; (void)n_in; (void)out_size; (void)d_ws; (void)ws_size;
    const float* xyz = (const float*)d_in[0];
    float* out    = (float*)d_out;
    float* nbr    = out + NBR_OFF;
    float* center = out + CTR_OFF;
    float* idxo   = out + IDX_OFF;

    fps_kernel<<<NB, 1024, 0, stream>>>(xyz, center);
    knn_kernel<<<NB * NG, KT, 0, stream>>>(xyz, center, nbr, idxo);
}